// Round 14
// baseline (103.796 us; speedup 1.0000x reference)
//
#include <hip/hip_runtime.h>
#include <math.h>

constexpr int B_ = 64, Q_ = 900, N_ = 100, C_ = 256;
constexpr float EPSF = 1e-6f;
constexpr float BOX_W = 5.0f, GIOU_W = 2.0f, CLS_W = 1.0f;
constexpr int KP = 15;   // preds per lane: 64*15 >= 900
constexpr int T_ = 10;   // targets per chunk
constexpr int CH_ = 10;  // chunks
constexpr int NW = 16;   // waves per block (K2)
typedef unsigned long long u64;
typedef unsigned int u32;

__device__ __forceinline__ float giou_f(float px0, float py0, float px1, float py1, float pa,
                                        float tx0, float ty0, float tx1, float ty1, float ta) {
    float ltx = fmaxf(px0, tx0), lty = fmaxf(py0, ty0);
    float rbx = fminf(px1, tx1), rby = fminf(py1, ty1);
    float w = fmaxf(rbx - ltx, 0.0f), h = fmaxf(rby - lty, 0.0f);
    float inter = w * h;
    float uni = pa + ta - inter;
    float iou = inter / (uni + EPSF);
    float ex0 = fminf(px0, tx0), ey0 = fminf(py0, ty0);
    float ex1 = fmaxf(px1, tx1), ey1 = fmaxf(py1, ty1);
    float ew = fmaxf(ex1 - ex0, 0.0f), eh = fmaxf(ey1 - ey0, 0.0f);
    float earea = ew * eh;
    return iou - (earea - uni) / (earea + EPSF);
}

// order-preserving float->uint (bijective): a>b as float <=> f2ord(a)>f2ord(b)
__device__ __forceinline__ u32 f2ord(float f) {
    u32 u = __float_as_uint(f);
    return (u & 0x80000000u) ? ~u : (u | 0x80000000u);
}

// one DPP max step on a u64 (lo/hi moved with identical ctrl => consistent pair)
template <int CTRL, int ROW_MASK, int BANK_MASK>
__device__ __forceinline__ u64 dppmax64(u64 x) {
    u32 lo = (u32)x, hi = (u32)(x >> 32);
    u32 plo = (u32)__builtin_amdgcn_update_dpp((int)lo, (int)lo, CTRL, ROW_MASK, BANK_MASK, false);
    u32 phi = (u32)__builtin_amdgcn_update_dpp((int)hi, (int)hi, CTRL, ROW_MASK, BANK_MASK, false);
    u64 p = ((u64)phi << 32) | plo;
    return p > x ? p : x;
}
// wave64 u64 max (rocPRIM DPP pattern, result gathered from lane 63)
__device__ __forceinline__ u64 wave_max_u64(u64 x) {
    x = dppmax64<0x111, 0xf, 0xf>(x);  // row_shr:1
    x = dppmax64<0x112, 0xf, 0xf>(x);  // row_shr:2
    x = dppmax64<0x114, 0xf, 0xe>(x);  // row_shr:4
    x = dppmax64<0x118, 0xf, 0xc>(x);  // row_shr:8
    x = dppmax64<0x142, 0xa, 0xf>(x);  // row_bcast:15
    x = dppmax64<0x143, 0xc, 0xf>(x);  // row_bcast:31
    u32 lo = (u32)__builtin_amdgcn_readlane((int)(u32)x, 63);
    u32 hi = (u32)__builtin_amdgcn_readlane((int)(u32)(x >> 32), 63);
    return ((u64)hi << 32) | lo;
}

// ---- K1: whole-machine score matrix. 1600 blocks x 256 thr; wave = one (b,n) column ----
__global__ __launch_bounds__(256) void score_kernel(
    const float* __restrict__ pred_boxes,   // [B,Q,4] cxcywh
    const float* __restrict__ target_boxes, // [B,N,4] xyxy
    u32* __restrict__ g_mat)                // [B*N][KP][64] exact ords
{
    const int blk = blockIdx.x;
    const int b = blk / 25;
    const int wave = threadIdx.x >> 6;
    const int lane = threadIdx.x & 63;
    const int n = (blk % 25) * 4 + wave;
    const int bn = b * N_ + n;

    const float* t = target_boxes + (size_t)bn * 4;
    float tx0 = t[0], ty0 = t[1], tx1 = t[2], ty1 = t[3];
    float ta = (tx1 - tx0) * (ty1 - ty0);

    const float4* pbv = (const float4*)(pred_boxes + (size_t)b * Q_ * 4);
    u32* outp = g_mat + (size_t)bn * KP * 64;
    #pragma unroll
    for (int k = 0; k < KP; ++k) {
        int q = lane + (k << 6);
        u32 val = 0u;
        if (q < Q_) {
            float4 c = pbv[q];
            float x0 = c.x - 0.5f * c.z, y0 = c.y - 0.5f * c.w;
            float x1 = c.x + 0.5f * c.z, y1 = c.y + 0.5f * c.w;
            float pa = (x1 - x0) * (y1 - y0);
            float g = giou_f(x0, y0, x1, y1, pa, tx0, ty0, tx1, ty1, ta);
            val = f2ord(g);
        }
        outp[k * 64 + lane] = val;
    }
}

// ---- K2: resolve (u64-key DPP argmax) + BCE + box loss + finalize ----
__global__ __launch_bounds__(1024, 1) void resolve_kernel(
    const float* __restrict__ pred_boxes,
    const float* __restrict__ pred_logits,
    const float* __restrict__ target_boxes,
    const int*   __restrict__ target_labels,
    const u32*   __restrict__ g_mat,
    double* __restrict__ partial,
    u32* __restrict__ cnt,
    float* __restrict__ out)
{
    const int b = blockIdx.x;
    const int tid = threadIdx.x;
    const int lane = tid & 63;
    const int wid = tid >> 6;

    __shared__ u32 s_mat[2][T_ * KP][64];    // 76.8 KB double-buffered ord planes
    __shared__ float tx0s[N_], ty0s[N_], tx1s[N_], ty1s[N_], tas[N_];
    __shared__ int labs[N_], s_ms[N_];
    __shared__ double s_wred[NW];
    __shared__ int s_last;

    if (wid == 0) __builtin_amdgcn_s_setprio(1);  // keep the serial wave's issue priority up

    if (tid < N_) {
        const float4 t4 = ((const float4*)(target_boxes + (size_t)b * N_ * 4))[tid];
        tx0s[tid] = t4.x; ty0s[tid] = t4.y; tx1s[tid] = t4.z; ty1s[tid] = t4.w;
        tas[tid] = (t4.z - t4.x) * (t4.w - t4.y);
        labs[tid] = target_labels[b * N_ + tid];
    }
    const u32* gm = g_mat + (size_t)b * N_ * KP * 64;

    // prologue: staging waves copy chunk 0 (one column each)
    if (wid >= 1 && wid <= T_) {
        const int nl = wid - 1;
        const u32* src = gm + (size_t)nl * KP * 64;
        #pragma unroll
        for (int k = 0; k < KP; ++k)
            s_mat[0][nl * KP + k][lane] = src[k * 64 + lane];
    }
    __syncthreads();

    double acc = 0.0;
    u32 um = 0u;  // used bits among this lane's KP preds (resolve wave only)
    const float* lgbase = pred_logits + (size_t)b * Q_ * C_;

    // pipelined main loop: w0 resolves c | w1-10 copy c+1 | w11-15 BCE c-1
    for (int c = 0; c < CH_; ++c) {
        if (wid == 0) {
            const u32 (*smat)[64] = s_mat[c & 1];
            u32 wcur[KP];
            #pragma unroll
            for (int k = 0; k < KP; ++k) wcur[k] = smat[k][lane];
            #pragma unroll 1
            for (int nl = 0; nl < T_; ++nl) {
                const int n = c * T_ + nl;
                u32 wnext[KP];
                #pragma unroll
                for (int k = 0; k < KP; ++k)
                    wnext[k] = (nl + 1 < T_) ? smat[(nl + 1) * KP + k][lane] : 0u;
                // u64 keys: (ord<<10)|(1023-q) => max = (max ord, min q). tree-max, depth 4.
                u64 kk[16];
                #pragma unroll
                for (int k = 0; k < KP; ++k) {
                    u32 v = ((um >> k) & 1u) ? 0u : wcur[k];
                    kk[k] = ((u64)v << 10) | (u32)(1023 - (lane + (k << 6)));
                }
                kk[15] = 0ull;
                #pragma unroll
                for (int k = 0; k < 8; ++k) kk[k] = kk[k] > kk[k + 8] ? kk[k] : kk[k + 8];
                #pragma unroll
                for (int k = 0; k < 4; ++k) kk[k] = kk[k] > kk[k + 4] ? kk[k] : kk[k + 4];
                kk[0] = kk[0] > kk[2] ? kk[0] : kk[2];
                kk[1] = kk[1] > kk[3] ? kk[1] : kk[3];
                kk[0] = kk[0] > kk[1] ? kk[0] : kk[1];
                u64 m = wave_max_u64(kk[0]);
                int wq = 1023 - (int)(m & 1023u);
                if (lane == (wq & 63)) um |= 1u << (wq >> 6);
                if (lane == 0) s_ms[n] = wq;
                #pragma unroll
                for (int k = 0; k < KP; ++k) wcur[k] = wnext[k];
            }
        } else if (wid <= 10) {
            if (c + 1 < CH_) {
                const int nl = wid - 1;
                const u32* src = gm + (size_t)((c + 1) * T_ + nl) * KP * 64;
                #pragma unroll
                for (int k = 0; k < KP; ++k)
                    s_mat[(c + 1) & 1][nl * KP + k][lane] = src[k * 64 + lane];
            }
        } else {
            if (c >= 1) {
                // BCE for chunk c-1: 2 rows per wave (s_ms visible since last barrier)
                #pragma unroll
                for (int r = 0; r < 2; ++r) {
                    const int n = (c - 1) * T_ + (wid - 11) + r * 5;
                    int q = s_ms[n];
                    int lab = labs[n];
                    const float4 xv = *(const float4*)(lgbase + (size_t)q * C_ + lane * 4);
                    float xs[4] = {xv.x, xv.y, xv.z, xv.w};
                    int base = lane * 4;
                    #pragma unroll
                    for (int j = 0; j < 4; ++j) {
                        float x = xs[j];
                        float tt = (base + j == lab) ? 1.0f : 0.0f;
                        acc += (double)(fmaxf(x, 0.0f) - x * tt + log1pf(expf(-fabsf(x))));
                    }
                }
            }
        }
        __syncthreads();
    }

    // tail BCE: last chunk rows 90..99, waves 6..15 one row each
    if (wid >= 6) {
        const int n = (CH_ - 1) * T_ + (wid - 6);
        int q = s_ms[n];
        int lab = labs[n];
        const float4 xv = *(const float4*)(lgbase + (size_t)q * C_ + lane * 4);
        float xs[4] = {xv.x, xv.y, xv.z, xv.w};
        int base = lane * 4;
        #pragma unroll
        for (int j = 0; j < 4; ++j) {
            float x = xs[j];
            float tt = (base + j == lab) ? 1.0f : 0.0f;
            acc += (double)(fmaxf(x, 0.0f) - x * tt + log1pf(expf(-fabsf(x))));
        }
    }
    acc *= (double)CLS_W;

    // box losses: one target per thread (tid < 100)
    const float4* pbv = (const float4*)(pred_boxes + (size_t)b * Q_ * 4);
    if (tid < N_) {
        int q = s_ms[tid];
        float4 c = pbv[q];
        float tx0 = tx0s[tid], ty0 = ty0s[tid], tx1 = tx1s[tid], ty1 = ty1s[tid];
        float tcx = (tx0 + tx1) * 0.5f, tcy = (ty0 + ty1) * 0.5f;
        float tw = tx1 - tx0, th = ty1 - ty0;
        float l1 = fabsf(c.x - tcx) + fabsf(c.y - tcy) + fabsf(c.z - tw) + fabsf(c.w - th);
        float x0 = c.x - 0.5f * c.z, y0 = c.y - 0.5f * c.w;
        float x1 = c.x + 0.5f * c.z, y1 = c.y + 0.5f * c.w;
        float pa2 = (x1 - x0) * (y1 - y0);
        float g = giou_f(x0, y0, x1, y1, pa2, tx0, ty0, tx1, ty1, tas[tid]);
        acc += (double)(BOX_W * l1) + (double)(GIOU_W * (1.0f - g));
    }

    // reduce: per-wave f64 butterfly -> 16 partials -> serial fixed-order sum
    #pragma unroll
    for (int off = 32; off >= 1; off >>= 1) acc += __shfl_xor(acc, off);
    if (lane == 0) s_wred[wid] = acc;
    __syncthreads();

    if (tid == 0) {
        double s = 0.0;
        #pragma unroll
        for (int w = 0; w < NW; ++w) s += s_wred[w];
        __hip_atomic_store(&partial[b], s, __ATOMIC_RELEASE, __HIP_MEMORY_SCOPE_AGENT);
        u32 old = __hip_atomic_fetch_add(cnt, 1u, __ATOMIC_ACQ_REL, __HIP_MEMORY_SCOPE_AGENT);
        s_last = (old == (u32)(B_ - 1)) ? 1 : 0;
    }
    __syncthreads();
    if (s_last && tid < 64) {
        double v = __hip_atomic_load(&partial[lane], __ATOMIC_ACQUIRE, __HIP_MEMORY_SCOPE_AGENT);
        #pragma unroll
        for (int off = 32; off >= 1; off >>= 1) v += __shfl_xor(v, off);
        if (lane == 0) out[0] = (float)(v / (double)(B_ * N_));
    }
}

extern "C" void kernel_launch(void* const* d_in, const int* in_sizes, int n_in,
                              void* d_out, int out_size, void* d_ws, size_t ws_size,
                              hipStream_t stream) {
    const float* pred_boxes    = (const float*)d_in[0];
    const float* pred_logits   = (const float*)d_in[1];
    const float* target_boxes  = (const float*)d_in[2];
    const int*   target_labels = (const int*)d_in[3];
    float* out = (float*)d_out;

    char* ws = (char*)d_ws;
    u32*    g_mat   = (u32*)(ws);                     // 6400*15*64*4 = 24,576,000 B
    double* partial = (double*)(ws + 24576000);       // 64*8
    u32*    cnt     = (u32*)(ws + 24576512);          // 4

    (void)hipMemsetAsync(cnt, 0, sizeof(u32), stream);  // capture-safe memset node
    hipLaunchKernelGGL(score_kernel, dim3(1600), dim3(256), 0, stream,
                       pred_boxes, target_boxes, g_mat);
    hipLaunchKernelGGL(resolve_kernel, dim3(B_), dim3(1024), 0, stream,
                       pred_boxes, pred_logits, target_boxes, target_labels,
                       g_mat, partial, cnt, out);
}